// Round 7
// baseline (31.264 us; speedup 1.0000x reference)
//
#include <hip/hip_runtime.h>

// Problem constants (from reference): B=4, N=512, K=20, C=32
#define Bb 4
#define Nn 512
#define Kk 20
#define Cc 32

typedef float f32x4 __attribute__((ext_vector_type(4)));

// out[b, n, k, c1, c2] = trans[c1,c2] + length[k,c2] + slide[b,n,k,c2]
//                        + (k == (N-1)-n ? E[b,N-1,c1] : 0)
//                        + (n == 0 ? init[c2] : 0)
// slide[b,n,k,c2] = sum_{j=n}^{min(n+k,N)-1} E[b,j,c2]   (k frames, clipped)
//
// One block per (b,n). Wave 0 lanes 0..31 stage base[k][c2] = lens + slide
// (+init) in LDS (independent global loads + register prefix), barrier, then
// the k dimension is partitioned ACROSS the 4 waves (wave w owns k in
// [5w,5w+5)). Each wave covers the full 4KB (c1,c2) slab per k with 4 store
// instructions (lane l, inst i -> c1 = i*8 + l/8, q = l%8), so each wave's
// 20 stores are strictly ascending contiguous addresses (20KB sequential
// stream per wave) instead of 1KB chunks at 4KB stride. History: NT stores
// -13% (R3), store batching neutral (R4), low occupancy -28% (R5), LDS base
// staging +6% (R6).
__global__ __launch_bounds__(256) void semimarkov_scores_kernel(
    const float* __restrict__ trans,   // (C,C)
    const float* __restrict__ emis,    // (B,N,C)
    const float* __restrict__ initv,   // (C,)
    const float* __restrict__ lens,    // (K,C)
    float* __restrict__ out)           // (B, N-1, K, C, C)
{
    __shared__ float base[Kk][Cc];     // 2560 B

    const int tid  = threadIdx.x;
    const int wav  = tid >> 6;         // 0..3, owns k in [5*wav, 5*wav+5)
    const int lane = tid & 63;
    const int q    = lane & 7;         // float4 chunk along c2
    const int bn   = blockIdx.x;       // b*(N-1) + n
    const int b    = bn / (Nn - 1);
    const int n    = bn - b * (Nn - 1);

    // Per-lane invariants: 4 transition rows (c1 = i*8 + lane/8, i=0..3)
    f32x4 t4[4];
    float el[4];                       // eos addend per inst-row
    const int   k_eos = (Nn - 1) - n;  // >= 1 always
    const float* e_row = &emis[((size_t)b * Nn + (Nn - 1)) * Cc];
    #pragma unroll
    for (int i = 0; i < 4; ++i) {
        const int c1 = i * 8 + (lane >> 3);
        t4[i] = *reinterpret_cast<const f32x4*>(&trans[c1 * Cc + q * 4]);
        el[i] = (k_eos < Kk) ? e_row[c1] : 0.0f;
    }

    // Stage base[k][c2] with 32 lanes of wave 0.
    if (tid < Cc) {
        const int c2 = tid;
        float l[Kk], e[Kk];
        const float* ebs = &emis[((size_t)b * Nn + n) * Cc + c2];
        #pragma unroll
        for (int k = 0; k < Kk; ++k) {
            l[k] = lens[k * Cc + c2];                  // independent loads
            e[k] = (n + k < Nn) ? ebs[(size_t)k * Cc] : 0.0f;
        }
        float s = (n == 0) ? initv[c2] : 0.0f;
        #pragma unroll
        for (int k = 0; k < Kk; ++k) {
            base[k][c2] = l[k] + s;                    // slide[k] excludes frame n+k
            s += e[k];
        }
    }
    __syncthreads();

    // Wave-sequential store stream: 20KB ascending per wave.
    float* ob = &out[(size_t)bn * (size_t)(Kk * Cc * Cc)];
    #pragma unroll
    for (int kk = 0; kk < 5; ++kk) {
        const int k = wav * 5 + kk;
        const f32x4 b4 = *reinterpret_cast<const f32x4*>(&base[k][q * 4]);
        const bool eos = (k == k_eos);
        float* slab = ob + (size_t)k * (Cc * Cc);
        #pragma unroll
        for (int i = 0; i < 4; ++i) {
            f32x4 v = t4[i] + b4;
            if (eos) v += (f32x4)(el[i]);
            // byte offset i*1024 + lane*16  ->  float offset i*256 + lane*4
            *reinterpret_cast<f32x4*>(&slab[i * 256 + lane * 4]) = v;
        }
    }
}

extern "C" void kernel_launch(void* const* d_in, const int* in_sizes, int n_in,
                              void* d_out, int out_size, void* d_ws, size_t ws_size,
                              hipStream_t stream) {
    const float* trans = (const float*)d_in[0];   // (C,C)
    const float* emis  = (const float*)d_in[1];   // (B,N,C)
    const float* initv = (const float*)d_in[2];   // (C,)
    const float* lens  = (const float*)d_in[3];   // (K,C)
    float* out = (float*)d_out;                   // (B, N-1, K, C, C)

    const int grid = Bb * (Nn - 1);               // 2044 blocks
    semimarkov_scores_kernel<<<grid, 256, 0, stream>>>(trans, emis, initv, lens, out);
}